// Round 9
// baseline (283.248 us; speedup 1.0000x reference)
//
#include <hip/hip_runtime.h>
#include <hip/hip_bf16.h>
#include <math.h>

#define F_IN 256
#define HEADS 8
#define NEG_SLOPE 0.2f
#define PAD 64

typedef float f32x4  __attribute__((ext_vector_type(4)));
typedef _Float16 f16x8 __attribute__((ext_vector_type(8)));
typedef _Float16 half4 __attribute__((ext_vector_type(4)));

// wave-local LDS ordering fence (guide rule #18)
static __device__ __forceinline__ void lds_fence() {
    asm volatile("s_waitcnt lgkmcnt(0)" ::: "memory");
    __builtin_amdgcn_sched_barrier(0);
}

// ---------------------------------------------------------------------------
// Fused kernel, 256 threads. Blocks [0,nsc): counting-sort edges into padded
// u16 CSR (cursor doubles as degree). Blocks [nsc, nsc+ng): barrier-free
// direct-to-register GEMM H2 = f16(X) @ f16(W) (fp32 acc, fp16 out) with
// fused per-head attention dots. No LDS, no __syncthreads in the GEMM —
// waves stream independently, latency hidden by TLP.
// GEMM geometry: block tile 64 rows x 256 cols; 4 waves share the rows,
// wave w owns cols w*64..w*64+63 (4x4 16x16 fragments).
// ---------------------------------------------------------------------------
__global__ __launch_bounds__(256) void fused_kernel(
    const float* __restrict__ X, const float* __restrict__ W,
    const float* __restrict__ att_src, const float* __restrict__ att_dst,
    const int* __restrict__ ei, int* __restrict__ cursor,
    unsigned short* __restrict__ padded, _Float16* __restrict__ H2,
    float* __restrict__ a_src, float* __restrict__ a_dst,
    int M, int E, int E2, int nsc)
{
    const int t = threadIdx.x;

    if ((int)blockIdx.x < nsc) {
        // ---- scatter path ----
        const int e = (int)blockIdx.x * 256 + t;
        if (e >= E2) return;
        int src, dst;
        if (e < E) { src = ei[e]; dst = ei[(size_t)E + e]; }
        else       { src = e - E; dst = e - E; }
        const int pos = atomicAdd(&cursor[dst], 1);
        if (pos < PAD) padded[(size_t)dst * PAD + pos] = (unsigned short)src;
        return;
    }

    // ---- gemm + attdot path (barrier-free) ----
    const int lane = t & 63;
    const int w    = t >> 6;            // wave 0..3 -> col quarter
    const int row0 = ((int)blockIdx.x - nsc) * 64;

    const int kgf  = lane >> 4;         // k-group 0..3 (8 k each)
    const int lrow = lane & 15;

    f32x4 acc[4][4];
#pragma unroll
    for (int i = 0; i < 4; ++i)
#pragma unroll
        for (int j = 0; j < 4; ++j)
            acc[i][j] = (f32x4){0.f, 0.f, 0.f, 0.f};

    const int colbase = w * 64 + lrow;

    for (int step = 0; step < 8; ++step) {
        const int k0 = step * 32 + kgf * 8;
        // ---- A fragments direct from X (fp32 -> f16 in reg) ----
        f16x8 af[4];
#pragma unroll
        for (int i = 0; i < 4; ++i) {
            const int row = row0 + i * 16 + lrow;
            float4 v0 = make_float4(0.f, 0.f, 0.f, 0.f);
            float4 v1 = make_float4(0.f, 0.f, 0.f, 0.f);
            if (row < M) {
                const float* xp = X + (size_t)row * 256 + k0;
                v0 = *(const float4*)xp;
                v1 = *(const float4*)(xp + 4);
            }
            af[i][0] = (_Float16)v0.x; af[i][1] = (_Float16)v0.y;
            af[i][2] = (_Float16)v0.z; af[i][3] = (_Float16)v0.w;
            af[i][4] = (_Float16)v1.x; af[i][5] = (_Float16)v1.y;
            af[i][6] = (_Float16)v1.z; af[i][7] = (_Float16)v1.w;
        }
        // ---- B fragments direct from fp32 W (L2-resident) ----
#pragma unroll
        for (int j = 0; j < 4; ++j) {
            const float* wp = W + (size_t)k0 * 256 + colbase + j * 16;
            f16x8 bf;
#pragma unroll
            for (int jj = 0; jj < 8; ++jj)
                bf[jj] = (_Float16)wp[(size_t)jj * 256];
#pragma unroll
            for (int i = 0; i < 4; ++i)
                acc[i][j] = __builtin_amdgcn_mfma_f32_16x16x32_f16(af[i], bf, acc[i][j], 0, 0, 0);
        }
    }

    // ---- epilogue: H2 store + attdot via reduce-scatter over 16 lanes ----
    // C/D layout: col = colbase + j*16, row = rbase + i*16 + r.
    // Head ownership: h0 = w*2 (j=0,1), h1 = w*2+1 (j=2,3).
    const int rbase = row0 + (lane >> 4) * 4;
    const float as0 = att_src[colbase],      as1 = att_src[colbase + 16];
    const float as2 = att_src[colbase + 32], as3 = att_src[colbase + 48];
    const float ad0 = att_dst[colbase],      ad1 = att_dst[colbase + 16];
    const float ad2 = att_dst[colbase + 32], ad3 = att_dst[colbase + 48];

#pragma unroll
    for (int i = 0; i < 4; ++i) {
#pragma unroll
        for (int r = 0; r < 4; ++r) {
            const int row = rbase + i * 16 + r;
            const bool ok = row < M;
            if (ok) {
#pragma unroll
                for (int j = 0; j < 4; ++j)
                    H2[(size_t)row * 256 + colbase + j * 16] = (_Float16)acc[i][j][r];
            }
            float ps0 = acc[i][0][r] * as0 + acc[i][1][r] * as1;   // src, h0
            float ps1 = acc[i][2][r] * as2 + acc[i][3][r] * as3;   // src, h1
            float pd0 = acc[i][0][r] * ad0 + acc[i][1][r] * ad1;   // dst, h0
            float pd1 = acc[i][2][r] * ad2 + acc[i][3][r] * ad3;   // dst, h1
            // reduce-scatter over 16 lanes: bit3 -> src/dst, bit2 -> head
            ps0 += __shfl_xor(ps0, 8); ps1 += __shfl_xor(ps1, 8);
            pd0 += __shfl_xor(pd0, 8); pd1 += __shfl_xor(pd1, 8);
            float va = (lrow & 8) ? pd0 : ps0;
            float vb = (lrow & 8) ? pd1 : ps1;
            va += __shfl_xor(va, 4);
            vb += __shfl_xor(vb, 4);
            float vc = (lrow & 4) ? vb : va;
            vc += __shfl_xor(vc, 2);
            vc += __shfl_xor(vc, 1);
            if (ok && (lrow & 3) == 0) {
                float* base = (lrow & 8) ? a_dst : a_src;
                const int h = w * 2 + ((lrow >> 2) & 1);
                base[(size_t)row * 8 + h] = vc;
            }
        }
    }
}

// ---------------------------------------------------------------------------
// Aggregate: one wave per dst node, padded u16 CSR (base n*PAD, deg=cursor).
// Sweep 1: alpha -> LDS (lane -> head lane&7), per-head max.
// Sweep 2: w = __expf(alpha - m) once per (edge,head), accumulate sum.
// Phase B (r7-proven form): lane covers channels 4*lane..+3 (head lane>>3),
// fp16 half4 gathers, unroll 4, weight broadcast from LDS.
// ---------------------------------------------------------------------------
__global__ __launch_bounds__(256) void aggregate_kernel(
    const _Float16* __restrict__ H2, const float* __restrict__ Asrc,
    const float* __restrict__ Adst, const int* __restrict__ cursor,
    const unsigned short* __restrict__ padded, const float* __restrict__ bias,
    float* __restrict__ out, int N)
{
    __shared__ float aw[4][PAD][8];     // 8 KB
    __shared__ int   sid[4][PAD];       // 1 KB

    const int n = (int)((blockIdx.x * blockDim.x + threadIdx.x) >> 6);
    const int lane = threadIdx.x & 63;
    const int wid  = (threadIdx.x >> 6) & 3;
    if (n >= N) return;

    const size_t beg = (size_t)n * PAD;
    int deg = cursor[n];
    if (deg > PAD) deg = PAD;

    const int h2 = lane & 7;
    const float adst2 = Adst[(size_t)n * 8 + h2];

    // sweep 1: alpha -> LDS (+ register cache), per-head max
    float areg[4];
    float m = -INFINITY;
    {
        int tt = 0;
        for (int i = lane; i < deg * 8; i += 64, ++tt) {
            const int e = i >> 3;
            const int s = (int)padded[beg + e];
            float a = Asrc[(size_t)s * 8 + h2] + adst2;
            a = a > 0.f ? a : NEG_SLOPE * a;
            aw[wid][e][h2] = a;
            if (h2 == 0) sid[wid][e] = s;
            if (tt < 4) areg[tt] = a;
            m = fmaxf(m, a);
        }
    }
#pragma unroll
    for (int off = 8; off < 64; off <<= 1) m = fmaxf(m, __shfl_xor(m, off));
    lds_fence();

    // sweep 2: w = exp(alpha - m), accumulate sum, store unnormalized w
    float ssum = 0.f;
    {
        int tt = 0;
        for (int i = lane; i < deg * 8; i += 64, ++tt) {
            const int e = i >> 3;
            const float a = (tt < 4) ? areg[tt] : aw[wid][e][h2];
            const float w = __expf(a - m);
            ssum += w;
            aw[wid][e][h2] = w;
        }
    }
#pragma unroll
    for (int off = 8; off < 64; off <<= 1) ssum += __shfl_xor(ssum, off);
    const float rdn = 1.f / (ssum + 1e-16f);
    lds_fence();

    // phase B: lane covers 4 channels, head = lane>>3, unroll 4
    const int h3 = lane >> 3;
    const float rdn3 = __shfl(rdn, h3);

    float4 acc0 = make_float4(0.f, 0.f, 0.f, 0.f);
    float4 acc1 = make_float4(0.f, 0.f, 0.f, 0.f);
    int e = 0;
    for (; e + 4 <= deg; e += 4) {
        const int4 s4 = *(const int4*)&sid[wid][e];
        const float w0 = aw[wid][e + 0][h3] * rdn3;
        const float w1 = aw[wid][e + 1][h3] * rdn3;
        const float w2 = aw[wid][e + 2][h3] * rdn3;
        const float w3 = aw[wid][e + 3][h3] * rdn3;
        const half4 g0 = *(const half4*)(H2 + (size_t)s4.x * 256 + lane * 4);
        const half4 g1 = *(const half4*)(H2 + (size_t)s4.y * 256 + lane * 4);
        const half4 g2 = *(const half4*)(H2 + (size_t)s4.z * 256 + lane * 4);
        const half4 g3 = *(const half4*)(H2 + (size_t)s4.w * 256 + lane * 4);
        acc0.x += (float)g0[0] * w0; acc0.y += (float)g0[1] * w0; acc0.z += (float)g0[2] * w0; acc0.w += (float)g0[3] * w0;
        acc1.x += (float)g1[0] * w1; acc1.y += (float)g1[1] * w1; acc1.z += (float)g1[2] * w1; acc1.w += (float)g1[3] * w1;
        acc0.x += (float)g2[0] * w2; acc0.y += (float)g2[1] * w2; acc0.z += (float)g2[2] * w2; acc0.w += (float)g2[3] * w2;
        acc1.x += (float)g3[0] * w3; acc1.y += (float)g3[1] * w3; acc1.z += (float)g3[2] * w3; acc1.w += (float)g3[3] * w3;
    }
    for (; e < deg; ++e) {
        const int s0 = sid[wid][e];
        const float w0 = aw[wid][e][h3] * rdn3;
        const half4 g0 = *(const half4*)(H2 + (size_t)s0 * 256 + lane * 4);
        acc0.x += (float)g0[0] * w0; acc0.y += (float)g0[1] * w0; acc0.z += (float)g0[2] * w0; acc0.w += (float)g0[3] * w0;
    }
    float4 acc;
    acc.x = acc0.x + acc1.x; acc.y = acc0.y + acc1.y;
    acc.z = acc0.z + acc1.z; acc.w = acc0.w + acc1.w;

    const float4 b = *(const float4*)(bias + lane * 4);
    float4 o;
    o.x = acc.x + b.x; o.y = acc.y + b.y; o.z = acc.z + b.z; o.w = acc.w + b.w;
    o.x = o.x > 0.f ? o.x : __expf(o.x) - 1.f;
    o.y = o.y > 0.f ? o.y : __expf(o.y) - 1.f;
    o.z = o.z > 0.f ? o.z : __expf(o.z) - 1.f;
    o.w = o.w > 0.f ? o.w : __expf(o.w) - 1.f;
    *(float4*)(out + (size_t)n * 256 + lane * 4) = o;
}

// ---------------------------------------------------------------------------
extern "C" void kernel_launch(void* const* d_in, const int* in_sizes, int n_in,
                              void* d_out, int out_size, void* d_ws, size_t ws_size,
                              hipStream_t stream)
{
    const float* x       = (const float*)d_in[0];
    const int*   ei      = (const int*)  d_in[1];
    const float* W       = (const float*)d_in[2];
    const float* att_src = (const float*)d_in[3];
    const float* att_dst = (const float*)d_in[4];
    const float* bias    = (const float*)d_in[5];
    float* out = (float*)d_out;

    const int N  = in_sizes[0] / F_IN;   // 50000
    const int E  = in_sizes[1] / 2;      // 800000
    const int E2 = E + N;                // + self loops
    const int NSC = (E2 + 255) / 256;    // scatter blocks
    const int NG  = (N + 63) / 64;       // gemm blocks

    // workspace layout (256B aligned sections)
    char* ws = (char*)d_ws;
    size_t o = 0;
    auto take = [&](size_t bytes) { void* p = ws + o; o = (o + bytes + 255) & ~(size_t)255; return p; };
    _Float16* H2           = (_Float16*)take((size_t)N * 256 * 2);   // 25.6 MB
    float* a_src           = (float*)take((size_t)N * 8 * 4);
    float* a_dst           = (float*)take((size_t)N * 8 * 4);
    int*   cursor          = (int*)  take((size_t)N * 4);
    unsigned short* padded = (unsigned short*)take((size_t)N * PAD * 2);  // 6.4 MB
    (void)ws_size; (void)n_in; (void)out_size;

    // 0) zero cursor (ws is poisoned 0xAA before every call)
    hipMemsetAsync(cursor, 0, (size_t)N * 4, stream);

    // 1) scatter + barrier-free gemm + attdot in one dispatch
    fused_kernel<<<NSC + NG, 256, 0, stream>>>(
        x, W, att_src, att_dst, ei, cursor, padded, H2, a_src, a_dst,
        N, E, E2, NSC);

    // 2) softmax + aggregate + bias + ELU
    aggregate_kernel<<<(N * 64 + 255) / 256, 256, 0, stream>>>(
        H2, a_src, a_dst, cursor, padded, bias, out, N);
}